// Round 5
// baseline (444.811 us; speedup 1.0000x reference)
//
#include <hip/hip_runtime.h>
#include <hip/hip_bf16.h>

typedef __attribute__((ext_vector_type(8))) short short8;
typedef __attribute__((ext_vector_type(4))) float f32x4;
typedef __attribute__((ext_vector_type(2))) unsigned int u32x2;

#define DIN  4096
#define DOUT 4096
#define NTOK 16384

static __device__ __forceinline__ unsigned short f2b(float f) {
  union { __hip_bfloat16 h; unsigned short u; } cv;
  cv.h = __float2bfloat16(f);
  return cv.u;
}

static __device__ __forceinline__ short8 pack8(float4 f0, float4 f1) {
  short8 s;
  s[0] = (short)f2b(f0.x); s[1] = (short)f2b(f0.y);
  s[2] = (short)f2b(f0.z); s[3] = (short)f2b(f0.w);
  s[4] = (short)f2b(f1.x); s[5] = (short)f2b(f1.y);
  s[6] = (short)f2b(f1.z); s[7] = (short)f2b(f1.w);
  return s;
}

// ------------- prologue (merged): transpose+convert weights to bf16 ----------
// btt_r[n][b][k] f32 -> Rt[n][c=k][b] bf16 ; btt_l[m][j][a] f32 -> Lt[m][a][j]
__global__ __launch_bounds__(256) void prep(const float* __restrict__ r,
                                            const float* __restrict__ l,
                                            unsigned short* __restrict__ rt,
                                            unsigned short* __restrict__ lt) {
  __shared__ unsigned short tile[128 * 68];
  const int q = threadIdx.x;
  if (blockIdx.x < 64) {
    const int n = blockIdx.x;
#pragma unroll
    for (int it = 0; it < 8; ++it) {
      const int idx = q + it * 256;           // float4 units
      const int b = idx >> 5, k4 = idx & 31;
      const float4 v = *(const float4*)(r + (size_t)n * 8192 + b * 128 + k4 * 4);
      unsigned int lo = (unsigned)f2b(v.x) | ((unsigned)f2b(v.y) << 16);
      unsigned int hi = (unsigned)f2b(v.z) | ((unsigned)f2b(v.w) << 16);
      u32x2 pk = {lo, hi};
      *(u32x2*)((char*)tile + (b * 264 + k4 * 8)) = pk;   // [b][k] stride 132
    }
    __syncthreads();
#pragma unroll
    for (int it = 0; it < 32; ++it) {
      const int o = q + it * 256;             // o = c*64 + b
      const int c = o >> 6, b = o & 63;
      rt[(size_t)n * 8192 + o] = tile[b * 132 + c];
    }
  } else {
    const int m = blockIdx.x - 64;
#pragma unroll
    for (int it = 0; it < 8; ++it) {
      const int idx = q + it * 256;
      const int j = idx >> 4, a4 = idx & 15;
      const float4 v = *(const float4*)(l + (size_t)m * 8192 + j * 64 + a4 * 4);
      unsigned int lo = (unsigned)f2b(v.x) | ((unsigned)f2b(v.y) << 16);
      unsigned int hi = (unsigned)f2b(v.z) | ((unsigned)f2b(v.w) << 16);
      u32x2 pk = {lo, hi};
      *(u32x2*)((char*)tile + (j * 136 + a4 * 8)) = pk;   // [j][a] stride 68
    }
    __syncthreads();
#pragma unroll
    for (int it = 0; it < 32; ++it) {
      const int o = q + it * 256;             // o = a*128 + j
      const int a = o >> 7, j = o & 127;
      lt[(size_t)m * 8192 + o] = tile[j * 68 + a];
    }
  }
}

// ---------------- fused kernel: h lives only in LDS --------------------------
// block = 16 tokens, 8 waves. 4 groups of 16 n.
// stage1 (per group): wave w computes n = g*16 + w*2 + {0,1}:
//   D(c-major) = mfma(A=Rt[n], B=x)  -> LDS h[nl][m][t][r] bf16, bit6-XOR swizzle
// stage2: wave w owns m in [8w, 8w+8): acc[mi][at] += mfma(A=Lt[m], B=h-frag)
// barriers: raw s_barrier + lgkmcnt(0) only -> x prefetch survives (vmcnt kept)
__global__ __launch_bounds__(512) void fused(const float* __restrict__ x,
                                             const unsigned short* __restrict__ rt,
                                             const unsigned short* __restrict__ lt,
                                             const float* __restrict__ bias,
                                             float* __restrict__ y) {
  __shared__ unsigned short hlds[32768];      // 64 KB: [16 nl][64 m][16 t][2 r]
  const int t0 = blockIdx.x * 16;
  const int tid = threadIdx.x, w = tid >> 6, lane = tid & 63;
  const int l15 = lane & 15, l4 = lane >> 4;

  const float* xrow = x + (size_t)(t0 + l15) * DIN + l4 * 8;

  f32x4 acc[8][4];
#pragma unroll
  for (int mi = 0; mi < 8; ++mi)
#pragma unroll
    for (int at = 0; at < 4; ++at) acc[mi][at] = (f32x4){0.f, 0.f, 0.f, 0.f};

  float4 xA[2][2][2], xB[2][2][2];            // [np][ks][half] register prefetch

  auto LOADX = [&](int g, float4 (&xb)[2][2][2]) {
#pragma unroll
    for (int np = 0; np < 2; ++np) {
      const float* p = xrow + (size_t)(g * 16 + w * 2 + np) * 64;
#pragma unroll
      for (int ks = 0; ks < 2; ++ks)
#pragma unroll
        for (int h = 0; h < 2; ++h)
          xb[np][ks][h] = *(const float4*)(p + ks * 32 + h * 4);
    }
  };

  auto STAGE1 = [&](int g, float4 (&xb)[2][2][2]) {
#pragma unroll
    for (int np = 0; np < 2; ++np) {
      const int n = g * 16 + w * 2 + np;
      const int nl = w * 2 + np;
      const short8 xf0 = pack8(xb[np][0][0], xb[np][0][1]);
      const short8 xf1 = pack8(xb[np][1][0], xb[np][1][1]);
      const unsigned short* rb = rt + (size_t)n * 8192 + l15 * 64 + l4 * 8;
#pragma unroll
      for (int ct = 0; ct < 8; ++ct) {
        const short8 r0 = *(const short8*)(rb + ct * 1024);
        const short8 r1 = *(const short8*)(rb + ct * 1024 + 32);
        f32x4 s = {0.f, 0.f, 0.f, 0.f};
        s = __builtin_amdgcn_mfma_f32_16x16x32_bf16(r0, xf0, s, 0, 0, 0);
        s = __builtin_amdgcn_mfma_f32_16x16x32_bf16(r1, xf1, s, 0, 0, 0);
        // D: row = c = ct*16 + l4*4 + jj, col = t = l15
        const int m0 = ct * 8 + l4 * 2;
#pragma unroll
        for (int dd = 0; dd < 2; ++dd) {
          const int m = m0 + dd;
          const unsigned int pk =
              (unsigned)f2b(s[2 * dd]) | ((unsigned)f2b(s[2 * dd + 1]) << 16);
          int byte = nl * 4096 + m * 64 + l15 * 4;
          byte ^= ((((m >> 1) ^ (nl >> 2)) & 1) << 6);
          *(unsigned int*)((char*)hlds + byte) = pk;
        }
      }
    }
  };

  auto STAGE2 = [&](int g) {
#pragma unroll
    for (int mi = 0; mi < 8; ++mi) {
      const int m = w * 8 + mi;
      union { unsigned int u[4]; short8 s; } hu;
#pragma unroll
      for (int q = 0; q < 4; ++q) {
        const int nl = l4 * 4 + q;
        int byte = nl * 4096 + m * 64 + l15 * 4;
        byte ^= ((((m >> 1) ^ (nl >> 2)) & 1) << 6);
        hu.u[q] = *(const unsigned int*)((char*)hlds + byte);
      }
      const unsigned short* lb = lt + (size_t)m * 8192 + l15 * 128 + g * 32 + l4 * 8;
#pragma unroll
      for (int at = 0; at < 4; ++at) {
        const short8 lf = *(const short8*)(lb + at * 2048);
        acc[mi][at] =
            __builtin_amdgcn_mfma_f32_16x16x32_bf16(lf, hu.s, acc[mi][at], 0, 0, 0);
      }
    }
  };

#define BARRIER()                                          \
  do {                                                     \
    asm volatile("s_waitcnt lgkmcnt(0)" ::: "memory");     \
    __builtin_amdgcn_s_barrier();                          \
    asm volatile("" ::: "memory");                         \
  } while (0)

  LOADX(0, xA);
  LOADX(1, xB); STAGE1(0, xA); BARRIER(); STAGE2(0); BARRIER();
  LOADX(2, xA); STAGE1(1, xB); BARRIER(); STAGE2(1); BARRIER();
  LOADX(3, xB); STAGE1(2, xA); BARRIER(); STAGE2(2); BARRIER();
                STAGE1(3, xB); BARRIER(); STAGE2(3);

  // epilogue: y = acc + bias, float4 stores
#pragma unroll
  for (int mi = 0; mi < 8; ++mi) {
    const int m = w * 8 + mi;
    float* yb = y + (size_t)(t0 + l15) * DOUT + m * 64 + l4 * 4;
    const float* bb = bias + m * 64 + l4 * 4;
#pragma unroll
    for (int at = 0; at < 4; ++at) {
      const float4 bv = *(const float4*)(bb + at * 16);
      float4 o;
      o.x = acc[mi][at][0] + bv.x;
      o.y = acc[mi][at][1] + bv.y;
      o.z = acc[mi][at][2] + bv.z;
      o.w = acc[mi][at][3] + bv.w;
      *(float4*)(yb + at * 16) = o;
    }
  }
#undef BARRIER
}

extern "C" void kernel_launch(void* const* d_in, const int* in_sizes, int n_in,
                              void* d_out, int out_size, void* d_ws, size_t ws_size,
                              hipStream_t stream) {
  const float* x    = (const float*)d_in[0];
  const float* bl   = (const float*)d_in[1];
  const float* br   = (const float*)d_in[2];
  const float* bias = (const float*)d_in[3];
  float* y = (float*)d_out;

  unsigned short* rt  = (unsigned short*)d_ws;           // 1 MB
  unsigned short* ltw = rt + 64 * 8192;                  // 1 MB

  prep<<<128, 256, 0, stream>>>(br, bl, rt, ltw);
  fused<<<NTOK / 16, 512, 0, stream>>>(x, rt, ltw, bias, y);
}